// Round 5
// baseline (545.599 us; speedup 1.0000x reference)
//
#include <hip/hip_runtime.h>
#include <hip/hip_bf16.h>

#define NN 50000
#define EE 600000
#define DD 128
#define LL 3
#define LN_EPS 1e-5f

// src-chunking for L2 locality in the gather
#define NC 4
#define CHUNK 12500            // NC*CHUNK == NN; 12500 rows * 256B = 3.2MB < 4MiB L2/XCD
#define NK (NC * NN)           // number of (chunk,dst) keys
#define SCAN_NB ((NK + 255) / 256)   // 782

typedef __attribute__((ext_vector_type(8))) short short8;
typedef __attribute__((ext_vector_type(4))) float floatx4;

__device__ inline unsigned short f2bf(float f) {
    union { float f; unsigned u; } a; a.f = f;
    unsigned r = a.u + 0x7fffu + ((a.u >> 16) & 1u);  // RNE (finite values)
    return (unsigned short)(r >> 16);
}

// ---------------- CSR build (keys = chunk*NN + dst) ----------------

__global__ void hist_kernel(const int* __restrict__ src, const int* __restrict__ dst,
                            int* __restrict__ cnt) {
    int i = blockIdx.x * blockDim.x + threadIdx.x;
    if (i >= EE + NN) return;
    int s, d;
    if (i < EE) { s = src[i]; d = dst[i]; }
    else        { s = i - EE; d = s; }
    atomicAdd(&cnt[(s / CHUNK) * NN + d], 1);
}

__global__ void dinv_kernel(const int* __restrict__ cnt, float* __restrict__ dinv) {
    int i = blockIdx.x * blockDim.x + threadIdx.x;
    if (i >= NN) return;
    int deg = cnt[i] + cnt[NN + i] + cnt[2 * NN + i] + cnt[3 * NN + i];  // incl self-loop
    dinv[i] = rsqrtf((float)deg);
}

__global__ __launch_bounds__(256) void scan1_kernel(const int* __restrict__ cnt,
                                                    int* __restrict__ blocksum) {
    __shared__ int red[4];
    int i = blockIdx.x * 256 + threadIdx.x;
    int v = (i < NK) ? cnt[i] : 0;
    int s = v;
    #pragma unroll
    for (int off = 32; off > 0; off >>= 1) s += __shfl_down(s, off);
    if ((threadIdx.x & 63) == 0) red[threadIdx.x >> 6] = s;
    __syncthreads();
    if (threadIdx.x == 0) blocksum[blockIdx.x] = red[0] + red[1] + red[2] + red[3];
}

__global__ __launch_bounds__(1024) void scan2_kernel(const int* __restrict__ blocksum,
                                                     int* __restrict__ blockpre,
                                                     int* __restrict__ rowoff) {
    __shared__ int s[1024];
    int t = threadIdx.x;
    int v = (t < SCAN_NB) ? blocksum[t] : 0;
    s[t] = v;
    __syncthreads();
    #pragma unroll
    for (int off = 1; off < 1024; off <<= 1) {
        int add = (t >= off) ? s[t - off] : 0;
        __syncthreads();
        s[t] += add;
        __syncthreads();
    }
    if (t < SCAN_NB) blockpre[t] = s[t] - v;
    if (t == 1023) rowoff[NK] = s[1023];
}

__global__ __launch_bounds__(256) void scan3_kernel(const int* __restrict__ cnt,
                                                    const int* __restrict__ blockpre,
                                                    int* __restrict__ rowoff,
                                                    int* __restrict__ cursor) {
    __shared__ int s[256];
    int t = threadIdx.x;
    int i = blockIdx.x * 256 + t;
    int v = (i < NK) ? cnt[i] : 0;
    s[t] = v;
    __syncthreads();
    #pragma unroll
    for (int off = 1; off < 256; off <<= 1) {
        int add = (t >= off) ? s[t - off] : 0;
        __syncthreads();
        s[t] += add;
        __syncthreads();
    }
    if (i < NK) {
        int r = blockpre[blockIdx.x] + s[t] - v;
        rowoff[i] = r;
        cursor[i] = r;
    }
}

__global__ void fill_kernel(const int* __restrict__ src, const int* __restrict__ dst,
                            int* __restrict__ cursor, int* __restrict__ csrc) {
    int i = blockIdx.x * blockDim.x + threadIdx.x;
    if (i >= EE + NN) return;
    int s, d;
    if (i < EE) { s = src[i]; d = dst[i]; }
    else        { s = i - EE; d = s; }
    int pos = atomicAdd(&cursor[(s / CHUNK) * NN + d], 1);
    csrc[pos] = s;
}

// ---------------- W transpose to bf16: Wt[l][n][k] = bf16(W[l][k][n]) --------

__global__ void wt_kernel(const float* __restrict__ W, unsigned short* __restrict__ Wt) {
    int i = blockIdx.x * blockDim.x + threadIdx.x;   // l*16384 + n*128 + k
    if (i >= LL * DD * DD) return;
    int l = i >> 14;
    int n = (i >> 7) & 127;
    int k = i & 127;
    Wt[i] = f2bf(W[(l << 14) + k * DD + n]);
}

// ---------------- MFMA GEMM: Cb[n] = bf16(dinv[n] * (A[n] @ W)) -------------
// 32 rows/block, 256 threads = 4 waves. Wave w: rows (w>>1)*16, cols (w&1)*64.

#define ALD 136   // padded row stride in shorts

template <typename AT>
__global__ __launch_bounds__(256) void gemm_mfma(const AT* __restrict__ A,
                                                 const unsigned short* __restrict__ Wt,
                                                 const float* __restrict__ dinv,
                                                 unsigned short* __restrict__ Cb) {
    __shared__ unsigned short alds[32 * ALD];
    int tid = threadIdx.x;
    int lane = tid & 63;
    int w = tid >> 6;
    int rowbase = blockIdx.x * 32;

    int cbase = (w & 1) * 64;
    int nIdx = cbase + (lane & 15);
    int kq = (lane >> 4) * 8;
    short8 bfr[4][4];
    #pragma unroll
    for (int j = 0; j < 4; j++)
        #pragma unroll
        for (int t = 0; t < 4; t++)
            bfr[j][t] = *(const short8*)&Wt[(nIdx + j * 16) * DD + t * 32 + kq];

    {
        int r = tid >> 3;
        int k0 = (tid & 7) * 16;
        int grow = rowbase + r;
        unsigned short* dstp = &alds[r * ALD + k0];
        if (grow < NN) {
            const AT* ap = &A[(size_t)grow * DD + k0];
            if constexpr (sizeof(AT) == 4) {
                float4 v0 = *(const float4*)&ap[0];
                float4 v1 = *(const float4*)&ap[4];
                float4 v2 = *(const float4*)&ap[8];
                float4 v3 = *(const float4*)&ap[12];
                float fv[16] = {v0.x,v0.y,v0.z,v0.w, v1.x,v1.y,v1.z,v1.w,
                                v2.x,v2.y,v2.z,v2.w, v3.x,v3.y,v3.z,v3.w};
                unsigned short uv[16];
                #pragma unroll
                for (int q = 0; q < 16; q++) uv[q] = f2bf(fv[q]);
                *(uint4*)&dstp[0] = *(uint4*)&uv[0];
                *(uint4*)&dstp[8] = *(uint4*)&uv[8];
            } else {
                *(uint4*)&dstp[0] = *(const uint4*)&ap[0];
                *(uint4*)&dstp[8] = *(const uint4*)&ap[8];
            }
        } else {
            uint4 z = make_uint4(0, 0, 0, 0);
            *(uint4*)&dstp[0] = z;
            *(uint4*)&dstp[8] = z;
        }
    }
    __syncthreads();

    int rbase = (w >> 1) * 16;
    int mrow = rbase + (lane & 15);
    floatx4 acc[4] = {{0.f,0.f,0.f,0.f},{0.f,0.f,0.f,0.f},
                      {0.f,0.f,0.f,0.f},{0.f,0.f,0.f,0.f}};
    #pragma unroll
    for (int t = 0; t < 4; t++) {
        short8 a = *(const short8*)&alds[mrow * ALD + t * 32 + kq];
        #pragma unroll
        for (int j = 0; j < 4; j++)
            acc[j] = __builtin_amdgcn_mfma_f32_16x16x32_bf16(a, bfr[j][t], acc[j], 0, 0, 0);
    }

    int gnode0 = rowbase + rbase + (lane >> 4) * 4;
    #pragma unroll
    for (int i = 0; i < 4; i++) {
        int node = gnode0 + i;
        if (node < NN) {
            float dv = dinv[node];
            #pragma unroll
            for (int j = 0; j < 4; j++)
                Cb[(size_t)node * DD + cbase + j * 16 + (lane & 15)] = f2bf(acc[j][i] * dv);
        }
    }
}

// ---------------- fused aggregate + bias + LayerNorm + PReLU ----------------
// 256 threads = 16 groups of 16 lanes; group handles 8 nodes (128 nodes/block).
// Chunk loop OUTERMOST: all resident blocks read the same 3.2MB tbuf chunk.
// Lane l owns features [8l,8l+8); acc[8 nodes][8 feats] in registers.

#define NPG 8      // nodes per group
#define NPB 128    // nodes per block

template <typename OUT>
__global__ __launch_bounds__(256) void agg_ln_kernel(
    const unsigned short* __restrict__ Tb, const int* __restrict__ rowoff,
    const int* __restrict__ csrc, const float* __restrict__ dinv,
    const float* __restrict__ bias, const float* __restrict__ lnw,
    const float* __restrict__ lnb, const float* __restrict__ alphas, int layer,
    OUT* __restrict__ out) {
    int g = threadIdx.x >> 4;
    int lane = threadIdx.x & 15;
    int n0 = blockIdx.x * NPB + g * NPG;
    int f8 = lane * 8;

    float acc[NPG][8] = {};
    for (int c = 0; c < NC; c++) {
        const int* ro = rowoff + c * NN;
        #pragma unroll
        for (int j = 0; j < NPG; j++) {
            int node = n0 + j;
            if (node >= NN) continue;
            int e0 = ro[node], e1 = ro[node + 1];
            for (int e = e0; e < e1; e++) {
                int s = csrc[e];
                uint4 t = *(const uint4*)&Tb[(size_t)s * DD + f8];
                unsigned uu[4] = {t.x, t.y, t.z, t.w};
                #pragma unroll
                for (int q = 0; q < 4; q++) {
                    union { unsigned x; float f; } lo, hi;
                    lo.x = uu[q] << 16;
                    hi.x = uu[q] & 0xffff0000u;
                    acc[j][2 * q]     += lo.f;
                    acc[j][2 * q + 1] += hi.f;
                }
            }
        }
    }

    float4 b0 = *(const float4*)&bias[f8];
    float4 b1 = *(const float4*)&bias[f8 + 4];
    float4 w0 = *(const float4*)&lnw[f8];
    float4 w1 = *(const float4*)&lnw[f8 + 4];
    float4 c0 = *(const float4*)&lnb[f8];
    float4 c1 = *(const float4*)&lnb[f8 + 4];
    float bv[8] = {b0.x, b0.y, b0.z, b0.w, b1.x, b1.y, b1.z, b1.w};
    float wv[8] = {w0.x, w0.y, w0.z, w0.w, w1.x, w1.y, w1.z, w1.w};
    float cv[8] = {c0.x, c0.y, c0.z, c0.w, c1.x, c1.y, c1.z, c1.w};
    float alpha = alphas[layer];

    #pragma unroll
    for (int j = 0; j < NPG; j++) {
        int node = n0 + j;
        if (node >= NN) continue;
        float dv = dinv[node];
        float a[8];
        float s1 = 0.f, s2 = 0.f;
        #pragma unroll
        for (int q = 0; q < 8; q++) {
            a[q] = fmaf(acc[j][q], dv, bv[q]);
            s1 += a[q]; s2 += a[q] * a[q];
        }
        #pragma unroll
        for (int off = 8; off > 0; off >>= 1) {
            s1 += __shfl_xor(s1, off, 16);
            s2 += __shfl_xor(s2, off, 16);
        }
        float mu = s1 * (1.f / DD);
        float var = s2 * (1.f / DD) - mu * mu;
        float rstd = rsqrtf(var + LN_EPS);
        float yv[8];
        #pragma unroll
        for (int q = 0; q < 8; q++) {
            float y = (a[q] - mu) * rstd * wv[q] + cv[q];
            yv[q] = (y >= 0.f) ? y : alpha * y;
        }
        if constexpr (sizeof(OUT) == 2) {
            unsigned short pv[8];
            #pragma unroll
            for (int q = 0; q < 8; q++) pv[q] = f2bf(yv[q]);
            *(uint4*)&out[(size_t)node * DD + f8] = *(uint4*)&pv[0];
        } else {
            float* op = (float*)&out[(size_t)node * DD + f8];
            *(float4*)&op[0] = make_float4(yv[0], yv[1], yv[2], yv[3]);
            *(float4*)&op[4] = make_float4(yv[4], yv[5], yv[6], yv[7]);
        }
    }
}

// ---------------- launch ----------------

extern "C" void kernel_launch(void* const* d_in, const int* in_sizes, int n_in,
                              void* d_out, int out_size, void* d_ws, size_t ws_size,
                              hipStream_t stream) {
    const float* x    = (const float*)d_in[0];
    const int*   ei   = (const int*)d_in[1];
    const float* Ws   = (const float*)d_in[2];
    const float* bs   = (const float*)d_in[3];
    const float* lnw  = (const float*)d_in[4];
    const float* lnb  = (const float*)d_in[5];
    const float* alphas = (const float*)d_in[6];
    float* out = (float*)d_out;

    const int* src = ei;
    const int* dst = ei + EE;

    char* ws = (char*)d_ws;
    size_t off = 0;
    auto alloc = [&](size_t bytes) -> void* {
        void* p = ws + off;
        off = (off + bytes + 255) & ~(size_t)255;
        return p;
    };
    int*   cnt      = (int*)alloc((size_t)NK * sizeof(int));
    float* dinv     = (float*)alloc(NN * sizeof(float));
    int*   rowoff   = (int*)alloc((size_t)(NK + 1) * sizeof(int));
    int*   cursor   = (int*)alloc((size_t)NK * sizeof(int));
    int*   blocksum = (int*)alloc(SCAN_NB * sizeof(int));
    int*   blockpre = (int*)alloc(SCAN_NB * sizeof(int));
    int*   csrc     = (int*)alloc((size_t)(EE + NN) * sizeof(int));
    unsigned short* wt   = (unsigned short*)alloc((size_t)LL * DD * DD * sizeof(unsigned short));
    unsigned short* tbuf = (unsigned short*)alloc((size_t)NN * DD * sizeof(unsigned short));
    unsigned short* hbuf = (unsigned short*)alloc((size_t)NN * DD * sizeof(unsigned short));

    hipMemsetAsync(cnt, 0, (size_t)NK * sizeof(int), stream);
    hist_kernel<<<(EE + NN + 255) / 256, 256, 0, stream>>>(src, dst, cnt);
    dinv_kernel<<<(NN + 255) / 256, 256, 0, stream>>>(cnt, dinv);
    scan1_kernel<<<SCAN_NB, 256, 0, stream>>>(cnt, blocksum);
    scan2_kernel<<<1, 1024, 0, stream>>>(blocksum, blockpre, rowoff);
    scan3_kernel<<<SCAN_NB, 256, 0, stream>>>(cnt, blockpre, rowoff, cursor);
    fill_kernel<<<(EE + NN + 255) / 256, 256, 0, stream>>>(src, dst, cursor, csrc);
    wt_kernel<<<(LL * DD * DD + 255) / 256, 256, 0, stream>>>(Ws, wt);

    const int gemm_grid = (NN + 31) / 32;
    const int agg_grid = (NN + NPB - 1) / NPB;
    for (int l = 0; l < LL; l++) {
        const unsigned short* wl = wt + (size_t)l * DD * DD;
        if (l == 0)
            gemm_mfma<float><<<gemm_grid, 256, 0, stream>>>(x, wl, dinv, tbuf);
        else
            gemm_mfma<unsigned short><<<gemm_grid, 256, 0, stream>>>(hbuf, wl, dinv, tbuf);
        if (l == LL - 1)
            agg_ln_kernel<float><<<agg_grid, 256, 0, stream>>>(
                tbuf, rowoff, csrc, dinv, bs + l * DD, lnw + l * DD, lnb + l * DD, alphas, l, out);
        else
            agg_ln_kernel<unsigned short><<<agg_grid, 256, 0, stream>>>(
                tbuf, rowoff, csrc, dinv, bs + l * DD, lnw + l * DD, lnb + l * DD, alphas, l, hbuf);
    }
}

// Round 6
// 327.398 us; speedup vs baseline: 1.6665x; 1.6665x over previous
//
#include <hip/hip_runtime.h>
#include <hip/hip_bf16.h>

#define NN 50000
#define EE 600000
#define DD 128
#define LL 3
#define LN_EPS 1e-5f

// src-chunking for L2 locality in the gather
#define NC 4
#define CHUNK 12500            // NC*CHUNK == NN; 12500 rows * 256B = 3.2MB < 4MiB L2/XCD
#define NK (NC * NN)           // number of (chunk,dst) keys
#define SCAN_NB ((NK + 255) / 256)   // 782

typedef __attribute__((ext_vector_type(8))) short short8;
typedef __attribute__((ext_vector_type(4))) float floatx4;

__device__ inline unsigned short f2bf(float f) {
    union { float f; unsigned u; } a; a.f = f;
    unsigned r = a.u + 0x7fffu + ((a.u >> 16) & 1u);  // RNE (finite values)
    return (unsigned short)(r >> 16);
}

// ---------------- CSR build (keys = chunk*NN + dst; NO self-loops) ----------

__global__ void hist_kernel(const int* __restrict__ src, const int* __restrict__ dst,
                            int* __restrict__ cnt) {
    int i = blockIdx.x * blockDim.x + threadIdx.x;
    if (i >= EE) return;
    atomicAdd(&cnt[(src[i] / CHUNK) * NN + dst[i]], 1);
}

__global__ void dinv_kernel(const int* __restrict__ cnt, float* __restrict__ dinv) {
    int i = blockIdx.x * blockDim.x + threadIdx.x;
    if (i >= NN) return;
    int deg = cnt[i] + cnt[NN + i] + cnt[2 * NN + i] + cnt[3 * NN + i] + 1;  // + self-loop
    dinv[i] = rsqrtf((float)deg);
}

__global__ __launch_bounds__(256) void scan1_kernel(const int* __restrict__ cnt,
                                                    int* __restrict__ blocksum) {
    __shared__ int red[4];
    int i = blockIdx.x * 256 + threadIdx.x;
    int v = (i < NK) ? cnt[i] : 0;
    int s = v;
    #pragma unroll
    for (int off = 32; off > 0; off >>= 1) s += __shfl_down(s, off);
    if ((threadIdx.x & 63) == 0) red[threadIdx.x >> 6] = s;
    __syncthreads();
    if (threadIdx.x == 0) blocksum[blockIdx.x] = red[0] + red[1] + red[2] + red[3];
}

__global__ __launch_bounds__(1024) void scan2_kernel(const int* __restrict__ blocksum,
                                                     int* __restrict__ blockpre,
                                                     int* __restrict__ rowoff) {
    __shared__ int s[1024];
    int t = threadIdx.x;
    int v = (t < SCAN_NB) ? blocksum[t] : 0;
    s[t] = v;
    __syncthreads();
    #pragma unroll
    for (int off = 1; off < 1024; off <<= 1) {
        int add = (t >= off) ? s[t - off] : 0;
        __syncthreads();
        s[t] += add;
        __syncthreads();
    }
    if (t < SCAN_NB) blockpre[t] = s[t] - v;
    if (t == 1023) rowoff[NK] = s[1023];
}

__global__ __launch_bounds__(256) void scan3_kernel(const int* __restrict__ cnt,
                                                    const int* __restrict__ blockpre,
                                                    int* __restrict__ rowoff,
                                                    int* __restrict__ cursor) {
    __shared__ int s[256];
    int t = threadIdx.x;
    int i = blockIdx.x * 256 + t;
    int v = (i < NK) ? cnt[i] : 0;
    s[t] = v;
    __syncthreads();
    #pragma unroll
    for (int off = 1; off < 256; off <<= 1) {
        int add = (t >= off) ? s[t - off] : 0;
        __syncthreads();
        s[t] += add;
        __syncthreads();
    }
    if (i < NK) {
        int r = blockpre[blockIdx.x] + s[t] - v;
        rowoff[i] = r;
        cursor[i] = r;
    }
}

__global__ void fill_kernel(const int* __restrict__ src, const int* __restrict__ dst,
                            int* __restrict__ cursor, int* __restrict__ csrc) {
    int i = blockIdx.x * blockDim.x + threadIdx.x;
    if (i >= EE) return;
    int s = src[i];
    int pos = atomicAdd(&cursor[(s / CHUNK) * NN + dst[i]], 1);
    csrc[pos] = s;
}

// ---------------- W transpose to bf16: Wt[l][n][k] = bf16(W[l][k][n]) --------

__global__ void wt_kernel(const float* __restrict__ W, unsigned short* __restrict__ Wt) {
    int i = blockIdx.x * blockDim.x + threadIdx.x;   // l*16384 + n*128 + k
    if (i >= LL * DD * DD) return;
    int l = i >> 14;
    int n = (i >> 7) & 127;
    int k = i & 127;
    Wt[i] = f2bf(W[(l << 14) + k * DD + n]);
}

// ---------------- MFMA GEMM: Cb[n] = bf16(dinv[n] * (A[n] @ W)) -------------
// 32 rows/block, 256 threads = 4 waves. Wave w: rows (w>>1)*16, cols (w&1)*64.

#define ALD 136   // padded row stride in shorts

template <typename AT>
__global__ __launch_bounds__(256) void gemm_mfma(const AT* __restrict__ A,
                                                 const unsigned short* __restrict__ Wt,
                                                 const float* __restrict__ dinv,
                                                 unsigned short* __restrict__ Cb) {
    __shared__ unsigned short alds[32 * ALD];
    int tid = threadIdx.x;
    int lane = tid & 63;
    int w = tid >> 6;
    int rowbase = blockIdx.x * 32;

    int cbase = (w & 1) * 64;
    int nIdx = cbase + (lane & 15);
    int kq = (lane >> 4) * 8;
    short8 bfr[4][4];
    #pragma unroll
    for (int j = 0; j < 4; j++)
        #pragma unroll
        for (int t = 0; t < 4; t++)
            bfr[j][t] = *(const short8*)&Wt[(nIdx + j * 16) * DD + t * 32 + kq];

    {
        int r = tid >> 3;
        int k0 = (tid & 7) * 16;
        int grow = rowbase + r;
        unsigned short* dstp = &alds[r * ALD + k0];
        if (grow < NN) {
            const AT* ap = &A[(size_t)grow * DD + k0];
            if constexpr (sizeof(AT) == 4) {
                float4 v0 = *(const float4*)&ap[0];
                float4 v1 = *(const float4*)&ap[4];
                float4 v2 = *(const float4*)&ap[8];
                float4 v3 = *(const float4*)&ap[12];
                float fv[16] = {v0.x,v0.y,v0.z,v0.w, v1.x,v1.y,v1.z,v1.w,
                                v2.x,v2.y,v2.z,v2.w, v3.x,v3.y,v3.z,v3.w};
                unsigned short uv[16];
                #pragma unroll
                for (int q = 0; q < 16; q++) uv[q] = f2bf(fv[q]);
                *(uint4*)&dstp[0] = *(uint4*)&uv[0];
                *(uint4*)&dstp[8] = *(uint4*)&uv[8];
            } else {
                *(uint4*)&dstp[0] = *(const uint4*)&ap[0];
                *(uint4*)&dstp[8] = *(const uint4*)&ap[8];
            }
        } else {
            uint4 z = make_uint4(0, 0, 0, 0);
            *(uint4*)&dstp[0] = z;
            *(uint4*)&dstp[8] = z;
        }
    }
    __syncthreads();

    int rbase = (w >> 1) * 16;
    int mrow = rbase + (lane & 15);
    floatx4 acc[4] = {{0.f,0.f,0.f,0.f},{0.f,0.f,0.f,0.f},
                      {0.f,0.f,0.f,0.f},{0.f,0.f,0.f,0.f}};
    #pragma unroll
    for (int t = 0; t < 4; t++) {
        short8 a = *(const short8*)&alds[mrow * ALD + t * 32 + kq];
        #pragma unroll
        for (int j = 0; j < 4; j++)
            acc[j] = __builtin_amdgcn_mfma_f32_16x16x32_bf16(a, bfr[j][t], acc[j], 0, 0, 0);
    }

    int gnode0 = rowbase + rbase + (lane >> 4) * 4;
    #pragma unroll
    for (int i = 0; i < 4; i++) {
        int node = gnode0 + i;
        if (node < NN) {
            float dv = dinv[node];
            #pragma unroll
            for (int j = 0; j < 4; j++)
                Cb[(size_t)node * DD + cbase + j * 16 + (lane & 15)] = f2bf(acc[j][i] * dv);
        }
    }
}

// ---------------- fused aggregate + bias + LayerNorm + PReLU ----------------
// 128 threads = 8 groups of 16 lanes; group g handles node blockIdx*8+g.
// Chunk loop outermost (L2 locality); self-loop = own prescaled row (implicit).
// Lane l owns features [8l,8l+8): one dwordx4 (8 bf16) per edge row.

template <typename OUT>
__global__ __launch_bounds__(128) void agg_ln_kernel(
    const unsigned short* __restrict__ Tb, const int* __restrict__ rowoff,
    const int* __restrict__ csrc, const float* __restrict__ dinv,
    const float* __restrict__ bias, const float* __restrict__ lnw,
    const float* __restrict__ lnb, const float* __restrict__ alphas, int layer,
    OUT* __restrict__ out) {
    int g = threadIdx.x >> 4;
    int lane = threadIdx.x & 15;
    int node = blockIdx.x * 8 + g;
    if (node >= NN) return;
    int f8 = lane * 8;

    // seed with own prescaled row (self-loop)
    float acc[8];
    {
        uint4 t = *(const uint4*)&Tb[(size_t)node * DD + f8];
        unsigned uu[4] = {t.x, t.y, t.z, t.w};
        #pragma unroll
        for (int q = 0; q < 4; q++) {
            union { unsigned x; float f; } lo, hi;
            lo.x = uu[q] << 16;
            hi.x = uu[q] & 0xffff0000u;
            acc[2 * q]     = lo.f;
            acc[2 * q + 1] = hi.f;
        }
    }

    #pragma unroll
    for (int c = 0; c < NC; c++) {
        int e0 = rowoff[c * NN + node];
        int e1 = rowoff[c * NN + node + 1];
        for (int e = e0; e < e1; e++) {
            int s = csrc[e];
            uint4 t = *(const uint4*)&Tb[(size_t)s * DD + f8];
            unsigned uu[4] = {t.x, t.y, t.z, t.w};
            #pragma unroll
            for (int q = 0; q < 4; q++) {
                union { unsigned x; float f; } lo, hi;
                lo.x = uu[q] << 16;
                hi.x = uu[q] & 0xffff0000u;
                acc[2 * q]     += lo.f;
                acc[2 * q + 1] += hi.f;
            }
        }
    }

    float4 b0 = *(const float4*)&bias[f8];
    float4 b1 = *(const float4*)&bias[f8 + 4];
    float bv[8] = {b0.x, b0.y, b0.z, b0.w, b1.x, b1.y, b1.z, b1.w};
    float dv = dinv[node];
    float s1 = 0.f, s2 = 0.f;
    float a[8];
    #pragma unroll
    for (int q = 0; q < 8; q++) {
        a[q] = fmaf(acc[q], dv, bv[q]);
        s1 += a[q]; s2 += a[q] * a[q];
    }
    #pragma unroll
    for (int off = 8; off > 0; off >>= 1) {
        s1 += __shfl_xor(s1, off, 16);
        s2 += __shfl_xor(s2, off, 16);
    }
    float mu = s1 * (1.f / DD);
    float var = s2 * (1.f / DD) - mu * mu;
    float rstd = rsqrtf(var + LN_EPS);
    float alpha = alphas[layer];

    float4 w0 = *(const float4*)&lnw[f8];
    float4 w1 = *(const float4*)&lnw[f8 + 4];
    float4 c0 = *(const float4*)&lnb[f8];
    float4 c1 = *(const float4*)&lnb[f8 + 4];
    float wv[8] = {w0.x, w0.y, w0.z, w0.w, w1.x, w1.y, w1.z, w1.w};
    float cv[8] = {c0.x, c0.y, c0.z, c0.w, c1.x, c1.y, c1.z, c1.w};
    float yv[8];
    #pragma unroll
    for (int q = 0; q < 8; q++) {
        float y = (a[q] - mu) * rstd * wv[q] + cv[q];
        yv[q] = (y >= 0.f) ? y : alpha * y;
    }
    if constexpr (sizeof(OUT) == 2) {
        unsigned short pv[8];
        #pragma unroll
        for (int q = 0; q < 8; q++) pv[q] = f2bf(yv[q]);
        *(uint4*)&out[(size_t)node * DD + f8] = *(uint4*)&pv[0];
    } else {
        float* op = (float*)&out[(size_t)node * DD + f8];
        *(float4*)&op[0] = make_float4(yv[0], yv[1], yv[2], yv[3]);
        *(float4*)&op[4] = make_float4(yv[4], yv[5], yv[6], yv[7]);
    }
}

// ---------------- launch ----------------

extern "C" void kernel_launch(void* const* d_in, const int* in_sizes, int n_in,
                              void* d_out, int out_size, void* d_ws, size_t ws_size,
                              hipStream_t stream) {
    const float* x    = (const float*)d_in[0];
    const int*   ei   = (const int*)d_in[1];
    const float* Ws   = (const float*)d_in[2];
    const float* bs   = (const float*)d_in[3];
    const float* lnw  = (const float*)d_in[4];
    const float* lnb  = (const float*)d_in[5];
    const float* alphas = (const float*)d_in[6];
    float* out = (float*)d_out;

    const int* src = ei;
    const int* dst = ei + EE;

    char* ws = (char*)d_ws;
    size_t off = 0;
    auto alloc = [&](size_t bytes) -> void* {
        void* p = ws + off;
        off = (off + bytes + 255) & ~(size_t)255;
        return p;
    };
    int*   cnt      = (int*)alloc((size_t)NK * sizeof(int));
    float* dinv     = (float*)alloc(NN * sizeof(float));
    int*   rowoff   = (int*)alloc((size_t)(NK + 1) * sizeof(int));
    int*   cursor   = (int*)alloc((size_t)NK * sizeof(int));
    int*   blocksum = (int*)alloc(SCAN_NB * sizeof(int));
    int*   blockpre = (int*)alloc(SCAN_NB * sizeof(int));
    int*   csrc     = (int*)alloc((size_t)EE * sizeof(int));
    unsigned short* wt   = (unsigned short*)alloc((size_t)LL * DD * DD * sizeof(unsigned short));
    unsigned short* tbuf = (unsigned short*)alloc((size_t)NN * DD * sizeof(unsigned short));
    unsigned short* hbuf = (unsigned short*)alloc((size_t)NN * DD * sizeof(unsigned short));

    hipMemsetAsync(cnt, 0, (size_t)NK * sizeof(int), stream);
    hist_kernel<<<(EE + 255) / 256, 256, 0, stream>>>(src, dst, cnt);
    dinv_kernel<<<(NN + 255) / 256, 256, 0, stream>>>(cnt, dinv);
    scan1_kernel<<<SCAN_NB, 256, 0, stream>>>(cnt, blocksum);
    scan2_kernel<<<1, 1024, 0, stream>>>(blocksum, blockpre, rowoff);
    scan3_kernel<<<SCAN_NB, 256, 0, stream>>>(cnt, blockpre, rowoff, cursor);
    fill_kernel<<<(EE + 255) / 256, 256, 0, stream>>>(src, dst, cursor, csrc);
    wt_kernel<<<(LL * DD * DD + 255) / 256, 256, 0, stream>>>(Ws, wt);

    const int gemm_grid = (NN + 31) / 32;
    const int agg_grid = (NN + 7) / 8;
    for (int l = 0; l < LL; l++) {
        const unsigned short* wl = wt + (size_t)l * DD * DD;
        if (l == 0)
            gemm_mfma<float><<<gemm_grid, 256, 0, stream>>>(x, wl, dinv, tbuf);
        else
            gemm_mfma<unsigned short><<<gemm_grid, 256, 0, stream>>>(hbuf, wl, dinv, tbuf);
        if (l == LL - 1)
            agg_ln_kernel<float><<<agg_grid, 128, 0, stream>>>(
                tbuf, rowoff, csrc, dinv, bs + l * DD, lnw + l * DD, lnb + l * DD, alphas, l, out);
        else
            agg_ln_kernel<unsigned short><<<agg_grid, 128, 0, stream>>>(
                tbuf, rowoff, csrc, dinv, bs + l * DD, lnw + l * DD, lnb + l * DD, alphas, l, hbuf);
    }
}